// Round 2
// baseline (1632.797 us; speedup 1.0000x reference)
//
#include <hip/hip_runtime.h>
#include <stdint.h>
#include <stddef.h>

// Problem constants (fixed by the reference)
#define DIN  4096
#define DOUT 11008
#define MM   8192          // B*S = 4*2048
#define BM   128
#define BN   128
#define BK   64
#define NTM  (MM/BM)       // 64
#define NTN  (DOUT/BN)     // 86

typedef __bf16    bf16x8 __attribute__((ext_vector_type(8)));
typedef float     f32x4  __attribute__((ext_vector_type(4)));
typedef uint16_t  u16x8  __attribute__((ext_vector_type(8)));

// async global->LDS, 16B per lane; LDS dest must be the WAVE-uniform base
#define GLDS16(g, l) __builtin_amdgcn_global_load_lds(                         \
    (const __attribute__((address_space(1))) void*)(g),                        \
    (__attribute__((address_space(3))) void*)(l), 16, 0, 0)

__device__ __forceinline__ uint16_t f2bf(float f) {
    uint32_t u = __float_as_uint(f);
    u += 0x7fffu + ((u >> 16) & 1u);      // round-to-nearest-even
    return (uint16_t)(u >> 16);
}

// w_sim = mask ? w : sign(w)*bs   (sign(+-0)=0, matching jnp.sign)
__device__ __forceinline__ float wsim_val(float w, int m, float bs) {
    float s = (w > 0.f) ? bs : ((w < 0.f) ? -bs : 0.f);
    return m ? w : s;
}

// ---------------------------------------------------------------------------
// Mask format detection: flag=1 -> byte-packed (bool/uint8), flag=0 -> int32.
// Reads nelem/4 words: safe under BOTH layouts (covers all bytes if packed,
// first quarter of values if int32). int32 masks are exactly 0/1 -> no word>1.
// ---------------------------------------------------------------------------
__global__ void detect_mask_kernel(const uint32_t* __restrict__ mw, int* __restrict__ flag) {
    const size_t nw = (size_t)DOUT * DIN / 4;
    size_t i = (size_t)blockIdx.x * blockDim.x + threadIdx.x;
    const size_t stride = (size_t)gridDim.x * blockDim.x;
    int hit = 0;
    for (size_t j = i; j < nw; j += stride) {
        if (mw[j] > 1u) { hit = 1; break; }
    }
    if (hit) atomicOr(flag, 1);
}

// ---------------------------------------------------------------------------
// Build w_sim in bf16 (plain row-major [DOUT][DIN]) into workspace.
// ---------------------------------------------------------------------------
__global__ void convert_w_kernel(const float* __restrict__ w,
                                 const uint8_t* __restrict__ mask,
                                 const float* __restrict__ bsp,
                                 const int* __restrict__ flagp,
                                 uint16_t* __restrict__ outw) {
    const float bs = *bsp;
    const int f = *flagp;
    const size_t g  = (size_t)blockIdx.x * blockDim.x + threadIdx.x;
    const size_t e0 = g * 8;
    const float4 w0 = *(const float4*)(w + e0);
    const float4 w1 = *(const float4*)(w + e0 + 4);
    int mk[8];
    if (f) {
        uint64_t mm = *(const uint64_t*)(mask + e0);
#pragma unroll
        for (int j = 0; j < 8; ++j) mk[j] = (int)((mm >> (8 * j)) & 0xffu);
    } else {
        const int* mi = (const int*)mask;
        int4 ma = *(const int4*)(mi + e0);
        int4 mb = *(const int4*)(mi + e0 + 4);
        mk[0] = ma.x; mk[1] = ma.y; mk[2] = ma.z; mk[3] = ma.w;
        mk[4] = mb.x; mk[5] = mb.y; mk[6] = mb.z; mk[7] = mb.w;
    }
    u16x8 r;
    r[0] = f2bf(wsim_val(w0.x, mk[0], bs));
    r[1] = f2bf(wsim_val(w0.y, mk[1], bs));
    r[2] = f2bf(wsim_val(w0.z, mk[2], bs));
    r[3] = f2bf(wsim_val(w0.w, mk[3], bs));
    r[4] = f2bf(wsim_val(w1.x, mk[4], bs));
    r[5] = f2bf(wsim_val(w1.y, mk[5], bs));
    r[6] = f2bf(wsim_val(w1.z, mk[6], bs));
    r[7] = f2bf(wsim_val(w1.w, mk[7], bs));
    *(u16x8*)(outw + e0) = r;
}

__global__ void convert_x_kernel(const float* __restrict__ x, uint16_t* __restrict__ outx) {
    const size_t g  = (size_t)blockIdx.x * blockDim.x + threadIdx.x;
    const size_t e0 = g * 8;
    const float4 a = *(const float4*)(x + e0);
    const float4 b = *(const float4*)(x + e0 + 4);
    u16x8 r;
    r[0] = f2bf(a.x); r[1] = f2bf(a.y); r[2] = f2bf(a.z); r[3] = f2bf(a.w);
    r[4] = f2bf(b.x); r[5] = f2bf(b.y); r[6] = f2bf(b.z); r[7] = f2bf(b.w);
    *(u16x8*)(outx + e0) = r;
}

// ---------------------------------------------------------------------------
// GEMM: C[M,N] = X[M,K] * Wsim[N,K]^T + bias.  128x128 tile, BK=64, 4 waves,
// 16x16x32 bf16 MFMA, XOR-swizzled LDS (slot ^= row&7 at 16B granularity).
// AF/BF: 0 = operand pre-converted bf16 in ws (global_load_lds, source
// inverse-swizzled so linear LDS dest + swizzled read line up);
// 1 = convert on the fly (reg-staged, swizzled ds_write).
// ---------------------------------------------------------------------------
template <int AF, int BF>
__global__ __launch_bounds__(256) void gemm_kernel(
    const float* __restrict__ x, const uint16_t* __restrict__ xbf,
    const float* __restrict__ w, const uint16_t* __restrict__ wbf,
    const uint8_t* __restrict__ mask, const float* __restrict__ bsp,
    const int* __restrict__ flagp, const float* __restrict__ bias,
    float* __restrict__ out)
{
    __shared__ char smem[2 * BM * BK * 2];   // A tile 16KB + B tile 16KB
    char* sA = smem;
    char* sB = smem + BM * BK * 2;

    const int tid = threadIdx.x;
    const int wv = tid >> 6, ln = tid & 63;
    const int wr = wv >> 1, wc = wv & 1;     // 2x2 wave grid, 64x64 per wave

    const int bid = blockIdx.x;
    const int bm = bid % NTM, bn = bid / NTM;
    const int m0 = bm * BM, n0 = bn * BN;

    float bs = 0.f;
    int f = 0;
    if (BF) { bs = *bsp; f = *flagp; }

    const f32x4 z4 = {0.f, 0.f, 0.f, 0.f};
    f32x4 acc[4][4];
#pragma unroll
    for (int i = 0; i < 4; ++i)
#pragma unroll
        for (int j = 0; j < 4; ++j) acc[i][j] = z4;

    for (int kt = 0; kt < DIN / BK; ++kt) {
        const int k0 = kt * BK;

        // ---- stage B tile (rows n0..n0+127 of Wsim, k0..k0+63) ----
        if (BF == 0) {
#pragma unroll
            for (int i = 0; i < 4; ++i) {
                const int rl = i * 32 + wv * 8 + (ln >> 3);
                const int ck = (ln & 7) ^ (rl & 7);          // inverse-swizzled source
                const uint16_t* g = wbf + (size_t)(n0 + rl) * DIN + k0 + ck * 8;
                GLDS16(g, sB + i * 4096 + wv * 1024);
            }
        } else {
#pragma unroll
            for (int i = 0; i < 4; ++i) {
                const int rl = i * 32 + wv * 8 + (ln >> 3);
                const int sl = ln & 7;
                const int ck = sl ^ (rl & 7);
                const size_t e0 = (size_t)(n0 + rl) * DIN + k0 + ck * 8;
                const float4 wa = *(const float4*)(w + e0);
                const float4 wb = *(const float4*)(w + e0 + 4);
                int mk[8];
                if (f) {
                    uint64_t mm = *(const uint64_t*)(mask + e0);
#pragma unroll
                    for (int j = 0; j < 8; ++j) mk[j] = (int)((mm >> (8 * j)) & 0xffu);
                } else {
                    const int* mi = (const int*)mask;
                    int4 ma = *(const int4*)(mi + e0);
                    int4 mb = *(const int4*)(mi + e0 + 4);
                    mk[0] = ma.x; mk[1] = ma.y; mk[2] = ma.z; mk[3] = ma.w;
                    mk[4] = mb.x; mk[5] = mb.y; mk[6] = mb.z; mk[7] = mb.w;
                }
                u16x8 r;
                r[0] = f2bf(wsim_val(wa.x, mk[0], bs));
                r[1] = f2bf(wsim_val(wa.y, mk[1], bs));
                r[2] = f2bf(wsim_val(wa.z, mk[2], bs));
                r[3] = f2bf(wsim_val(wa.w, mk[3], bs));
                r[4] = f2bf(wsim_val(wb.x, mk[4], bs));
                r[5] = f2bf(wsim_val(wb.y, mk[5], bs));
                r[6] = f2bf(wsim_val(wb.z, mk[6], bs));
                r[7] = f2bf(wsim_val(wb.w, mk[7], bs));
                *(u16x8*)(sB + rl * 128 + sl * 16) = r;
            }
        }

        // ---- stage A tile (rows m0..m0+127 of X, k0..k0+63) ----
        if (AF == 0) {
#pragma unroll
            for (int i = 0; i < 4; ++i) {
                const int rl = i * 32 + wv * 8 + (ln >> 3);
                const int ck = (ln & 7) ^ (rl & 7);
                const uint16_t* g = xbf + (size_t)(m0 + rl) * DIN + k0 + ck * 8;
                GLDS16(g, sA + i * 4096 + wv * 1024);
            }
        } else {
#pragma unroll
            for (int i = 0; i < 4; ++i) {
                const int rl = i * 32 + wv * 8 + (ln >> 3);
                const int sl = ln & 7;
                const int ck = sl ^ (rl & 7);
                const float* g = x + (size_t)(m0 + rl) * DIN + k0 + ck * 8;
                const float4 aa = *(const float4*)g;
                const float4 bb = *(const float4*)(g + 4);
                u16x8 r;
                r[0] = f2bf(aa.x); r[1] = f2bf(aa.y); r[2] = f2bf(aa.z); r[3] = f2bf(aa.w);
                r[4] = f2bf(bb.x); r[5] = f2bf(bb.y); r[6] = f2bf(bb.z); r[7] = f2bf(bb.w);
                *(u16x8*)(sA + rl * 128 + sl * 16) = r;
            }
        }

        __syncthreads();   // compiler drains vmcnt/lgkmcnt before s_barrier

        // ---- compute: 2 k-chunks x (4x4) MFMAs ----
#pragma unroll
        for (int kc = 0; kc < 2; ++kc) {
            bf16x8 a[4], b[4];
            const int s = kc * 4 + (ln >> 4);       // 16B slot index within row
#pragma unroll
            for (int m = 0; m < 4; ++m) {
                const int row = wr * 64 + m * 16 + (ln & 15);
                a[m] = *(const bf16x8*)(sA + row * 128 + ((s ^ (row & 7)) << 4));
            }
#pragma unroll
            for (int n = 0; n < 4; ++n) {
                const int row = wc * 64 + n * 16 + (ln & 15);
                b[n] = *(const bf16x8*)(sB + row * 128 + ((s ^ (row & 7)) << 4));
            }
#pragma unroll
            for (int m = 0; m < 4; ++m)
#pragma unroll
                for (int n = 0; n < 4; ++n)
                    acc[m][n] = __builtin_amdgcn_mfma_f32_16x16x32_bf16(a[m], b[n], acc[m][n], 0, 0, 0);
        }

        __syncthreads();
    }

    // ---- epilogue: C/D layout col=lane&15, row=(lane>>4)*4+reg ----
#pragma unroll
    for (int n = 0; n < 4; ++n) {
        const int col = n0 + wc * 64 + n * 16 + (ln & 15);
        const float bv = bias[col];
#pragma unroll
        for (int m = 0; m < 4; ++m) {
            const int row0 = m0 + wr * 64 + m * 16 + (ln >> 4) * 4;
#pragma unroll
            for (int r = 0; r < 4; ++r)
                out[(size_t)(row0 + r) * DOUT + col] = acc[m][n][r] + bv;
        }
    }
}

// ---------------------------------------------------------------------------
extern "C" void kernel_launch(void* const* d_in, const int* in_sizes, int n_in,
                              void* d_out, int out_size, void* d_ws, size_t ws_size,
                              hipStream_t stream) {
    const float*   x    = (const float*)d_in[0];
    const float*   w    = (const float*)d_in[1];
    const float*   bias = (const float*)d_in[2];
    const uint8_t* mask = (const uint8_t*)d_in[3];
    const float*   bsp  = (const float*)d_in[4];
    float*         out  = (float*)d_out;

    int*      flag = (int*)d_ws;
    uint16_t* wbf  = (uint16_t*)((char*)d_ws + 256);
    uint16_t* xbf  = (uint16_t*)((char*)d_ws + 256 + (size_t)DOUT * DIN * 2);

    const size_t needW = 256 + (size_t)DOUT * DIN * 2;                      // ~90.2 MB
    const size_t needX = needW + (size_t)MM * DIN * 2;                      // ~157.3 MB

    hipMemsetAsync(d_ws, 0, 4, stream);                                     // zero flag
    detect_mask_kernel<<<1024, 256, 0, stream>>>((const uint32_t*)mask, flag);

    const bool preW = ws_size >= needW;
    const bool preX = ws_size >= needX;

    if (preW)
        convert_w_kernel<<<(DOUT * (size_t)DIN / 8) / 256, 256, 0, stream>>>(w, mask, bsp, flag, wbf);
    if (preX)
        convert_x_kernel<<<((size_t)MM * DIN / 8) / 256, 256, 0, stream>>>(x, xbf);

    const dim3 grid(NTM * NTN);   // 5504
    if (preW && preX)
        gemm_kernel<0, 0><<<grid, 256, 0, stream>>>(x, xbf, w, wbf, mask, bsp, flag, bias, out);
    else if (preW)
        gemm_kernel<1, 0><<<grid, 256, 0, stream>>>(x, xbf, w, wbf, mask, bsp, flag, bias, out);
    else
        gemm_kernel<1, 1><<<grid, 256, 0, stream>>>(x, xbf, w, wbf, mask, bsp, flag, bias, out);
}